// Round 4
// baseline (92.115 us; speedup 1.0000x reference)
//
#include <hip/hip_runtime.h>

#define HH 32
#define WW 32
#define NB 16
#define NPOS 512
#define TILE 8            // (h,w) positions per block
#define PPAD 516          // padded p-stride in LDS floats: 516 % 32 == 4 -> conflict-free float4 reads
#define NTHR 512          // 8 waves/block; 4 threads per cell (hi-split)
#define NBLK 128          // 1 block per 2 CUs -> co-residency trivial
#define NLAYERS 4

// Grid barrier, one counter slot per layer boundary (zeroed by hipMemsetAsync).
// Release add; poll with acquire but sleep long between polls so the
// buffer_inv storm of round 2 doesn't recur. Gate staging is NOT behind this
// barrier anymore — only the 64 KB state exchange is.
__device__ __forceinline__ void grid_barrier(int* cnt) {
    __syncthreads();                       // all waves drained (vmcnt(0) at barrier)
    if (threadIdx.x == 0) {
        __hip_atomic_fetch_add(cnt, 1, __ATOMIC_RELEASE, __HIP_MEMORY_SCOPE_AGENT);
        while (__hip_atomic_load(cnt, __ATOMIC_ACQUIRE, __HIP_MEMORY_SCOPE_AGENT) < NBLK) {
            __builtin_amdgcn_s_sleep(16);  // ~1024 cyc between polls
        }
    }
    __syncthreads();
}

__global__ __launch_bounds__(NTHR) void asic_fused(
    const float* __restrict__ x,     // (16,32,32)
    const float* __restrict__ tg,    // (4,512,32,32)
    float* __restrict__ bufA,
    float* __restrict__ bufB,
    float* __restrict__ out,
    int* __restrict__ bar)           // 3 zeroed counters
{
    __shared__ float lut[NLAYERS][TILE * PPAD];  // 66 KB: sigmoid(tg) for ALL layers
    __shared__ float red[NTHR];

    const int t   = threadIdx.x;          // 0..511
    const int hw0 = blockIdx.x * TILE;

    const int c   = t & 127;              // cell 0..127
    const int q   = t >> 7;               // hi-quarter 0..3
    const int b   = c >> 3;               // batch 0..15
    const int hwl = c & 7;
    const int h   = hw0 >> 5;
    const int w   = (hw0 & 31) + hwl;

    // ---- stage sigmoid(tg) for ALL 4 layers up front (independent of barriers)
    #pragma unroll
    for (int k = 0; k < 32; ++k) {
        int f     = t + NTHR * k;         // 0..16383
        int layer = f >> 12;
        int r     = f & 4095;
        int p     = r >> 3;
        int pos   = r & 7;
        float g = tg[(size_t)layer * NPOS * HH * WW + p * (HH * WW) + hw0 + pos];
        lut[layer][pos * PPAD + p] = 1.0f / (1.0f + __expf(-g));
    }

    const float* src = x;

    for (int layer = 0; layer < NLAYERS; ++layer) {
        float* dst = (layer == 3) ? out : ((layer & 1) ? bufB : bufA);

        // ---- gather 3x3 wrapped window from current state
        float cc[9];
        const float* sb = src + b * (HH * WW);
        #pragma unroll
        for (int i = 0; i < 3; ++i) {
            int row = ((h + i) & 31) * 32;
            #pragma unroll
            for (int j = 0; j < 3; ++j) {
                cc[3 * i + j] = sb[row + ((w + j - 1 + 32) & 31)];
            }
        }

        if (layer == 0) __syncthreads();  // luts ready (staging sync, once)

        // ---- v[lo] (m=4..8, MSB-first), u[hi] (m=0..3)
        float v[32];
        {
            float a2[2], a4[4], a8[8], a16[16];
            a2[0] = 1.0f - cc[4]; a2[1] = cc[4];
            #pragma unroll
            for (int i = 0; i < 2; ++i)  { a4[2*i]  = a2[i]  * (1.0f - cc[5]); a4[2*i+1]  = a2[i]  * cc[5]; }
            #pragma unroll
            for (int i = 0; i < 4; ++i)  { a8[2*i]  = a4[i]  * (1.0f - cc[6]); a8[2*i+1]  = a4[i]  * cc[6]; }
            #pragma unroll
            for (int i = 0; i < 8; ++i)  { a16[2*i] = a8[i]  * (1.0f - cc[7]); a16[2*i+1] = a8[i]  * cc[7]; }
            #pragma unroll
            for (int i = 0; i < 16; ++i) { v[2*i]   = a16[i] * (1.0f - cc[8]); v[2*i+1]   = a16[i] * cc[8]; }
        }
        float u[16];
        {
            float a2[2], a4[4], a8[8];
            a2[0] = 1.0f - cc[0]; a2[1] = cc[0];
            #pragma unroll
            for (int i = 0; i < 2; ++i) { a4[2*i] = a2[i] * (1.0f - cc[1]); a4[2*i+1] = a2[i] * cc[1]; }
            #pragma unroll
            for (int i = 0; i < 4; ++i) { a8[2*i] = a4[i] * (1.0f - cc[2]); a8[2*i+1] = a4[i] * cc[2]; }
            #pragma unroll
            for (int i = 0; i < 8; ++i) { u[2*i]  = a8[i] * (1.0f - cc[3]); u[2*i+1]  = a8[i] * cc[3]; }
        }

        // ---- partial dot over hi in [4q,4q+4): 32 broadcast b128 reads + 128 FMA
        const float4* lut4 = (const float4*)(&lut[layer][0] + hwl * PPAD);
        float acc = 0.0f;
        #pragma unroll
        for (int hh = 0; hh < 4; ++hh) {
            int hi = 4 * q + hh;
            float ps0 = 0.f, ps1 = 0.f, ps2 = 0.f, ps3 = 0.f;
            #pragma unroll
            for (int l4 = 0; l4 < 8; ++l4) {
                float4 L = lut4[hi * 8 + l4];
                ps0 = fmaf(L.x, v[4*l4+0], ps0);
                ps1 = fmaf(L.y, v[4*l4+1], ps1);
                ps2 = fmaf(L.z, v[4*l4+2], ps2);
                ps3 = fmaf(L.w, v[4*l4+3], ps3);
            }
            acc = fmaf(u[hi], (ps0 + ps1) + (ps2 + ps3), acc);
        }

        __syncthreads();      // red[] free from previous layer
        red[t] = acc;
        __syncthreads();

        if (t < 128) {
            float s = (red[t] + red[t + 128]) + (red[t + 256] + red[t + 384]);
            s = fminf(fmaxf(s, 0.0f), 1.0f);
            dst[b * (HH * WW) + h * 32 + w] = s;
        }

        if (layer < NLAYERS - 1) grid_barrier(bar + layer);
        src = dst;
    }
}

extern "C" void kernel_launch(void* const* d_in, const int* in_sizes, int n_in,
                              void* d_out, int out_size, void* d_ws, size_t ws_size,
                              hipStream_t stream) {
    const float* x  = (const float*)d_in[0];   // (16,32,32)
    const float* tg = (const float*)d_in[1];   // (4,512,32,32)
    float* out  = (float*)d_out;
    float* bufA = (float*)d_ws;                          // 64 KB
    float* bufB = bufA + NB * HH * WW;                   // 64 KB
    int*   bar  = (int*)((char*)d_ws + 256 * 1024);

    hipMemsetAsync(bar, 0, 4 * sizeof(int), stream);     // capture-safe
    asic_fused<<<NBLK, NTHR, 0, stream>>>(x, tg, bufA, bufB, out, bar);
}